// Round 1
// 1985.924 us; speedup vs baseline: 1.1409x; 1.1409x over previous
//
#include <hip/hip_runtime.h>
#include <hip/hip_bf16.h>
#include <math.h>

#define D 4096
#define T 8192
#define R 512
#define HD 128
#define NH 32

typedef unsigned short u16;
typedef u16 u16x8 __attribute__((ext_vector_type(8)));
typedef __bf16 bf16x8 __attribute__((ext_vector_type(8)));
typedef float f32x4 __attribute__((ext_vector_type(4)));

__device__ __forceinline__ u16 f2bf(float f) {
  unsigned u = __builtin_bit_cast(unsigned, f);
  u += 0x7FFFu + ((u >> 16) & 1u);   // RNE
  return (u16)(u >> 16);
}
__device__ __forceinline__ float bf2f(u16 b) {
  return __builtin_bit_cast(float, ((unsigned)b) << 16);
}
__device__ __forceinline__ bf16x8 ldb8(const u16* p) {
  return __builtin_bit_cast(bf16x8, *(const u16x8*)p);
}
// async global->LDS, 16B per lane; LDS dest = wave-uniform base + lane*16
__device__ __forceinline__ void async_cp16(void* gsrc, void* ldst) {
  typedef __attribute__((address_space(1))) void gvoid;
  typedef __attribute__((address_space(3))) void lvoid;
  __builtin_amdgcn_global_load_lds((gvoid*)gsrc, (lvoid*)ldst, 16, 0, 0);
}
#define MFMA(a, b, c) __builtin_amdgcn_mfma_f32_16x16x32_bf16(a, b, c, 0, 0, 0)

// raw barrier (no vmcnt drain) with compiler memory fence
__device__ __forceinline__ void wg_barrier() {
  asm volatile("" ::: "memory");
  __builtin_amdgcn_s_barrier();
  asm volatile("" ::: "memory");
}

// ---------------- LayerNorm (fp32 in -> bf16 out), one block per row ----------------
__global__ __launch_bounds__(256) void ln_bf16(
    const float* __restrict__ X, const float* __restrict__ w,
    const float* __restrict__ b, u16* __restrict__ out) {
  const int row = blockIdx.x, tid = threadIdx.x;
  const int lane = tid & 63, wv = tid >> 6;
  const float* xr = X + (long)row * D;
  float4 v[4];
  float s = 0.f, ss = 0.f;
#pragma unroll
  for (int i = 0; i < 4; ++i) {
    v[i] = *(const float4*)(xr + tid * 4 + i * 1024);
    s += v[i].x + v[i].y + v[i].z + v[i].w;
    ss += v[i].x * v[i].x + v[i].y * v[i].y + v[i].z * v[i].z + v[i].w * v[i].w;
  }
#pragma unroll
  for (int off = 32; off >= 1; off >>= 1) {
    s += __shfl_xor(s, off);
    ss += __shfl_xor(ss, off);
  }
  __shared__ float sw[4], ssw[4];
  if (lane == 0) { sw[wv] = s; ssw[wv] = ss; }
  __syncthreads();
  s = sw[0] + sw[1] + sw[2] + sw[3];
  ss = ssw[0] + ssw[1] + ssw[2] + ssw[3];
  const float mu = s * (1.f / D);
  const float var = ss * (1.f / D) - mu * mu;
  const float rstd = rsqrtf(var + 1e-5f);
#pragma unroll
  for (int i = 0; i < 4; ++i) {
    const int base = tid * 4 + i * 1024;
    const float4 wv4 = *(const float4*)(w + base);
    const float4 bv4 = *(const float4*)(b + base);
    ushort4 ov;
    ov.x = f2bf((v[i].x - mu) * rstd * wv4.x + bv4.x);
    ov.y = f2bf((v[i].y - mu) * rstd * wv4.y + bv4.y);
    ov.z = f2bf((v[i].z - mu) * rstd * wv4.z + bv4.z);
    ov.w = f2bf((v[i].w - mu) * rstd * wv4.w + bv4.w);
    *(ushort4*)(out + (long)row * D + base) = ov;
  }
}

// ------------- weight transpose + fp32->bf16 convert: W (K x N) -> Wt (N x K) -------------
__global__ __launch_bounds__(256) void wconv(const float* __restrict__ W,
                                             u16* __restrict__ Wt) {
  __shared__ float t[32][33];
  const int tx = threadIdx.x & 31, ty = threadIdx.x >> 5;
  const int n0 = blockIdx.x * 32, k0 = blockIdx.y * 32;
#pragma unroll
  for (int i = 0; i < 4; ++i)
    t[ty + i * 8][tx] = W[(long)(k0 + ty + i * 8) * D + n0 + tx];
  __syncthreads();
#pragma unroll
  for (int i = 0; i < 4; ++i)
    Wt[(long)(n0 + ty + i * 8) * D + k0 + tx] = f2bf(t[tx][ty + i * 8]);
}

// ---------------- legacy 128x128 GEMM (kept for the small KV GEMM, M=512) ----------------
// EPI: 1 = k/v split (v stored transposed)
template <int EPI>
__global__ __launch_bounds__(256) void gemm_bt(
    const u16* __restrict__ A, const u16* __restrict__ Bt, u16* __restrict__ ob,
    u16* __restrict__ ob2, float* __restrict__ of, const float* __restrict__ af,
    const u16* __restrict__ ab, float scale) {
  __shared__ u16 As[128 * 32];
  __shared__ u16 Bs[128 * 32];
  const int tid = threadIdx.x;
  const int bx = blockIdx.x, by = blockIdx.y;  // bx: n-block, by: m-block
  const int lane = tid & 63, w = tid >> 6;
  const int ln15 = lane & 15, q = lane >> 4;
  const int wm = (w >> 1) * 64, wn = (w & 1) * 64;

  const int c0 = tid, c1 = tid + 256;
  const u16* ag0 = A + (long)(by * 128 + (c0 >> 2)) * D + (c0 & 3) * 8;
  const u16* ag1 = A + (long)(by * 128 + (c1 >> 2)) * D + (c1 & 3) * 8;
  const u16* bg0 = Bt + (long)(bx * 128 + (c0 >> 2)) * D + (c0 & 3) * 8;
  const u16* bg1 = Bt + (long)(bx * 128 + (c1 >> 2)) * D + (c1 & 3) * 8;
  u16* al0 = As + (tid & ~63) * 8;
  u16* al1 = As + ((tid & ~63) + 256) * 8;
  u16* bl0 = Bs + (tid & ~63) * 8;
  u16* bl1 = Bs + ((tid & ~63) + 256) * 8;

  f32x4 acc[4][4];
#pragma unroll
  for (int i = 0; i < 4; ++i)
#pragma unroll
    for (int j = 0; j < 4; ++j) {
      f32x4 z = {0.f, 0.f, 0.f, 0.f};
      acc[i][j] = z;
    }

  for (int k0 = 0; k0 < D; k0 += 32) {
    __syncthreads();
    async_cp16((void*)(ag0 + k0), al0);
    async_cp16((void*)(ag1 + k0), al1);
    async_cp16((void*)(bg0 + k0), bl0);
    async_cp16((void*)(bg1 + k0), bl1);
    __syncthreads();
    bf16x8 av[4], bv[4];
#pragma unroll
    for (int i = 0; i < 4; ++i) av[i] = ldb8(As + (wm + i * 16 + ln15) * 32 + q * 8);
#pragma unroll
    for (int j = 0; j < 4; ++j) bv[j] = ldb8(Bs + (wn + j * 16 + ln15) * 32 + q * 8);
#pragma unroll
    for (int i = 0; i < 4; ++i)
#pragma unroll
      for (int j = 0; j < 4; ++j) acc[i][j] = MFMA(av[i], bv[j], acc[i][j]);
  }

#pragma unroll
  for (int i = 0; i < 4; ++i) {
    const int gmb = by * 128 + wm + i * 16 + q * 4;
#pragma unroll
    for (int j = 0; j < 4; ++j) {
      const int gn = bx * 128 + wn + j * 16 + ln15;
#pragma unroll
      for (int r = 0; r < 4; ++r) {
        const int gm = gmb + r;
        const float vacc = acc[i][j][r];
        const long idx = (long)gm * D + gn;
        if constexpr (EPI == 1) {
          if (gn < D)
            ob[idx] = f2bf(vacc);                       // k: (R x D)
          else
            ob2[(long)(gn - D) * R + gm] = f2bf(vacc);  // v^T: (D x R)
        } else {
          ob[idx] = f2bf(vacc * scale);
        }
      }
    }
  }
}

// ---------------- 256x256 8-phase GEMM (T2 swizzle + T3/T4 pipeline + T5 setprio) ----------------
// C = A(MxK) * Bt(NxK)^T, K = D. 512 threads = 8 waves (2M x 4N), per-wave C = 128x64.
// LDS: double-buffered A/B tiles of 256x64 bf16, split in 128-row halves = 128 KiB.
// EPI: 0 = bf16 store *scale; 2 = fp32 store acc + af; 3 = bf16 store gelu(acc);
//      4 = of += acc + bf2f(ab)
template <int MG>
__device__ __forceinline__ void readA(bf16x8 (&bA)[2][4], const u16* aB,
                                      int base, int cc0, int cc1) {
#pragma unroll
  for (int im = 0; im < 4; ++im) {
    bA[0][im] = ldb8(aB + (MG * 4 + im) * 1024 + base + cc0);
    bA[1][im] = ldb8(aB + (MG * 4 + im) * 1024 + base + cc1);
  }
}
template <int NJ0>
__device__ __forceinline__ void readB(bf16x8 (&bB)[2][4], const u16* bP,
                                      int base, int cc0, int cc1) {
#pragma unroll
  for (int nj = 0; nj < 2; ++nj) {
    bB[0][NJ0 + nj] = ldb8(bP + (NJ0 + nj) * 1024 + base + cc0);
    bB[1][NJ0 + nj] = ldb8(bP + (NJ0 + nj) * 1024 + base + cc1);
  }
}
template <int MG, int NJ0>
__device__ __forceinline__ void mfma16(f32x4 (&acc)[8][4], const bf16x8 (&bA)[2][4],
                                       const bf16x8 (&bB)[2][4]) {
#pragma unroll
  for (int im = 0; im < 4; ++im)
#pragma unroll
    for (int nj = 0; nj < 2; ++nj)
#pragma unroll
      for (int kk = 0; kk < 2; ++kk)
        acc[MG * 4 + im][NJ0 + nj] =
            MFMA(bA[kk][im], bB[kk][NJ0 + nj], acc[MG * 4 + im][NJ0 + nj]);
}

template <int EPI>
__global__ __launch_bounds__(512, 2) void gemm256(
    const u16* __restrict__ A, const u16* __restrict__ Bt, u16* __restrict__ ob,
    float* __restrict__ of, const float* __restrict__ af,
    const u16* __restrict__ ab, float scale) {
  __shared__ u16 As[2][2][8192];  // [buf][half(128 rows)][row*64 + swizzled col]
  __shared__ u16 Bs[2][2][8192];
  const int tid = threadIdx.x;
  const int bx = blockIdx.x, by = blockIdx.y;  // bx: n-block(256), by: m-block(256)
  const int lane = tid & 63, w = tid >> 6;
  const int ln15 = lane & 15, q = lane >> 4;
  const int wm = w >> 2, wn = w & 3;

  // ---- staging geometry: linear LDS dest, inverse-swizzled global source ----
  // physical 16B unit p = l*512 + tid -> row p>>3, physical slot p&7,
  // logical slot = (p&7) ^ (row&7)  (involution; read side applies same XOR)
  const int r0 = tid >> 3, s0 = (tid & 7) ^ (r0 & 7);
  const int r1 = 64 + r0, s1 = (tid & 7) ^ (r1 & 7);
  const long oA00 = (long)(by * 256 + r0) * D + s0 * 8;
  const long oA01 = (long)(by * 256 + r1) * D + s1 * 8;
  const long oA10 = (long)(by * 256 + 128 + r0) * D + s0 * 8;
  const long oA11 = (long)(by * 256 + 128 + r1) * D + s1 * 8;
  const long oB00 = (long)(bx * 256 + r0) * D + s0 * 8;
  const long oB01 = (long)(bx * 256 + r1) * D + s1 * 8;
  const long oB10 = (long)(bx * 256 + 128 + r0) * D + s0 * 8;
  const long oB11 = (long)(bx * 256 + 128 + r1) * D + s1 * 8;
  const int d0 = w * 512, d1 = 4096 + w * 512;  // wave-uniform LDS dest (u16 units)

  // ---- read-side swizzled offsets ----
  const int sw = ln15 & 7;
  const int cc0 = (q ^ sw) * 8;        // kk = 0: logical slot q
  const int cc1 = ((4 + q) ^ sw) * 8;  // kk = 1: logical slot 4+q
  const int baseA = ln15 * 64;
  const int baseB = (wn & 1) * 4096 + ln15 * 64;

  f32x4 acc[8][4];
#pragma unroll
  for (int i = 0; i < 8; ++i)
#pragma unroll
    for (int j = 0; j < 4; ++j) {
      f32x4 z = {0.f, 0.f, 0.f, 0.f};
      acc[i][j] = z;
    }

  auto stageA = [&](int buf, int kt) {
    async_cp16((void*)(A + oA00 + kt * 64), &As[buf][0][d0]);
    async_cp16((void*)(A + oA01 + kt * 64), &As[buf][0][d1]);
    async_cp16((void*)(A + oA10 + kt * 64), &As[buf][1][d0]);
    async_cp16((void*)(A + oA11 + kt * 64), &As[buf][1][d1]);
  };
  auto stageB = [&](int buf, int kt) {
    async_cp16((void*)(Bt + oB00 + kt * 64), &Bs[buf][0][d0]);
    async_cp16((void*)(Bt + oB01 + kt * 64), &Bs[buf][0][d1]);
    async_cp16((void*)(Bt + oB10 + kt * 64), &Bs[buf][1][d0]);
    async_cp16((void*)(Bt + oB11 + kt * 64), &Bs[buf][1][d1]);
  };

  // prologue: tile 0 in, drain, sync
  stageA(0, 0);
  stageB(0, 0);
  asm volatile("s_waitcnt vmcnt(0)" ::: "memory");
  wg_barrier();

  int cur = 0;
  for (int t = 0; t < D / 64; ++t) {
    const int nxt = cur ^ 1;
    const bool pf = (t + 1 < D / 64);
    const u16* aB = &As[cur][wm][0];
    const u16* bP = &Bs[cur][wn >> 1][0];
    bf16x8 bA[2][4], bB[2][4];
    // ---- phase 0: read A(m0-3) + B(n0-1); issue next A halves; C quadrant (m0-3, n0-1)
    readA<0>(bA, aB, baseA, cc0, cc1);
    readB<0>(bB, bP, baseB, cc0, cc1);
    if (pf) stageA(nxt, t + 1);
    wg_barrier();
    asm volatile("s_waitcnt lgkmcnt(0)" ::: "memory");
    __builtin_amdgcn_s_setprio(1);
    mfma16<0, 0>(acc, bA, bB);
    __builtin_amdgcn_s_setprio(0);
    wg_barrier();
    // ---- phase 1: read B(n2-3); issue next B halves; quadrant (m0-3, n2-3)
    readB<2>(bB, bP, baseB, cc0, cc1);
    if (pf) stageB(nxt, t + 1);
    wg_barrier();
    asm volatile("s_waitcnt lgkmcnt(0)" ::: "memory");
    __builtin_amdgcn_s_setprio(1);
    mfma16<0, 2>(acc, bA, bB);
    __builtin_amdgcn_s_setprio(0);
    wg_barrier();
    // ---- phase 2: read A(m4-7); quadrant (m4-7, n0-1)
    readA<1>(bA, aB, baseA, cc0, cc1);
    wg_barrier();
    asm volatile("s_waitcnt lgkmcnt(0)" ::: "memory");
    __builtin_amdgcn_s_setprio(1);
    mfma16<1, 0>(acc, bA, bB);
    __builtin_amdgcn_s_setprio(0);
    wg_barrier();
    // ---- phase 3: quadrant (m4-7, n2-3); counted-style wait (loads issued 2.5 phases ago)
    __builtin_amdgcn_s_setprio(1);
    mfma16<1, 2>(acc, bA, bB);
    __builtin_amdgcn_s_setprio(0);
    asm volatile("s_waitcnt vmcnt(0)" ::: "memory");
    wg_barrier();
    cur = nxt;
  }

  // epilogue; C-layout: col = lane&15, row = quad*4 + reg
#pragma unroll
  for (int mi = 0; mi < 8; ++mi) {
    const int gmb = by * 256 + wm * 128 + mi * 16 + q * 4;
#pragma unroll
    for (int nj = 0; nj < 4; ++nj) {
      const int gn = bx * 256 + wn * 64 + nj * 16 + ln15;
#pragma unroll
      for (int r = 0; r < 4; ++r) {
        const int gm = gmb + r;
        const float vacc = acc[mi][nj][r];
        const long idx = (long)gm * D + gn;
        if constexpr (EPI == 0) {
          ob[idx] = f2bf(vacc * scale);
        } else if constexpr (EPI == 2) {
          of[idx] = vacc + af[idx];
        } else if constexpr (EPI == 3) {
          ob[idx] = f2bf(0.5f * vacc * (1.f + erff(vacc * 0.7071067811865475f)));
        } else {
          of[idx] = of[idx] + vacc + bf2f(ab[idx]);
        }
      }
    }
  }
}

// ---------------- fused cross-attention, online softmax ----------------
// block = (64 tokens, 1 head); Q pre-scaled by 1/sqrt(HD); O written in-place over Q.
__global__ __launch_bounds__(256) void attn_fused(const u16* Q,
                                                  const u16* __restrict__ Kb,
                                                  const u16* __restrict__ Vt,
                                                  u16* O) {
  __shared__ u16 Qs[64 * 136];   // pad 128->136 (16B mult, 2-way banks)
  __shared__ u16 Ks[64 * 136];
  __shared__ u16 Vs[128 * 72];   // V^T chunk: 128 hd x 64 latents, pad 64->72
  __shared__ u16 Ps[4][16 * 72]; // per-wave P round-trip
  const int tid = threadIdx.x;
  const int lane = tid & 63, w = tid >> 6;
  const int ln15 = lane & 15, q = lane >> 4;
  const int t0 = blockIdx.x * 64, h = blockIdx.y;

#pragma unroll
  for (int it = 0; it < 4; ++it) {
    const int c = tid + it * 256;
    const int row = c >> 4, cj = c & 15;
    *(u16x8*)(Qs + row * 136 + cj * 8) =
        *(const u16x8*)(Q + (long)(t0 + row) * D + h * HD + cj * 8);
  }

  f32x4 o[8];
  float m_run[4], l_run[4];
#pragma unroll
  for (int t = 0; t < 8; ++t) {
    f32x4 z = {0.f, 0.f, 0.f, 0.f};
    o[t] = z;
  }
#pragma unroll
  for (int r = 0; r < 4; ++r) {
    m_run[r] = -1e30f;
    l_run[r] = 0.f;
  }

  for (int ch = 0; ch < 8; ++ch) {
    const int r0 = ch * 64;
    __syncthreads();
#pragma unroll
    for (int it = 0; it < 4; ++it) {
      const int c = tid + it * 256;
      const int row = c >> 4, cj = c & 15;
      *(u16x8*)(Ks + row * 136 + cj * 8) =
          *(const u16x8*)(Kb + (long)(r0 + row) * D + h * HD + cj * 8);
    }
#pragma unroll
    for (int it = 0; it < 4; ++it) {
      const int c = tid + it * 256;
      const int hd = c >> 3, rj = c & 7;
      *(u16x8*)(Vs + hd * 72 + rj * 8) =
          *(const u16x8*)(Vt + (long)(h * HD + hd) * R + r0 + rj * 8);
    }
    __syncthreads();

    // S chunk: wave w owns tokens w*16..+15; N = 64 latents, K = 128
    f32x4 s[4];
#pragma unroll
    for (int j = 0; j < 4; ++j) {
      f32x4 z = {0.f, 0.f, 0.f, 0.f};
      s[j] = z;
    }
#pragma unroll
    for (int kk = 0; kk < 4; ++kk) {
      const bf16x8 a = ldb8(Qs + (w * 16 + ln15) * 136 + kk * 32 + q * 8);
#pragma unroll
      for (int j = 0; j < 4; ++j) {
        const bf16x8 b = ldb8(Ks + (j * 16 + ln15) * 136 + kk * 32 + q * 8);
        s[j] = MFMA(a, b, s[j]);
      }
    }
    // online softmax (rows q*4+r live in this quad's 16 lanes)
    float mx[4], rs[4];
#pragma unroll
    for (int r = 0; r < 4; ++r)
      mx[r] = fmaxf(fmaxf(s[0][r], s[1][r]), fmaxf(s[2][r], s[3][r]));
#pragma unroll
    for (int off = 8; off >= 1; off >>= 1)
#pragma unroll
      for (int r = 0; r < 4; ++r) mx[r] = fmaxf(mx[r], __shfl_xor(mx[r], off));
#pragma unroll
    for (int r = 0; r < 4; ++r) {
      const float mn = fmaxf(m_run[r], mx[r]);
      const float al = __expf(m_run[r] - mn);
      m_run[r] = mn;
      float a2 = 0.f;
#pragma unroll
      for (int j = 0; j < 4; ++j) {
        const float p = __expf(s[j][r] - mn);
        s[j][r] = p;
        a2 += p;
      }
      rs[r] = a2;
      l_run[r] *= al;
#pragma unroll
      for (int t = 0; t < 8; ++t) o[t][r] *= al;
    }
#pragma unroll
    for (int off = 8; off >= 1; off >>= 1)
#pragma unroll
      for (int r = 0; r < 4; ++r) rs[r] += __shfl_xor(rs[r], off);
#pragma unroll
    for (int r = 0; r < 4; ++r) l_run[r] += rs[r];
    // P -> LDS (C-layout regs -> row-major), then PV with A-layout reads
#pragma unroll
    for (int j = 0; j < 4; ++j)
#pragma unroll
      for (int r = 0; r < 4; ++r)
        Ps[w][(q * 4 + r) * 72 + j * 16 + ln15] = f2bf(s[j][r]);
    __syncthreads();
#pragma unroll
    for (int kk = 0; kk < 2; ++kk) {
      const bf16x8 a = ldb8(Ps[w] + ln15 * 72 + kk * 32 + q * 8);
#pragma unroll
      for (int t = 0; t < 8; ++t) {
        const bf16x8 b = ldb8(Vs + (t * 16 + ln15) * 72 + kk * 32 + q * 8);
        o[t] = MFMA(a, b, o[t]);
      }
    }
  }
#pragma unroll
  for (int r = 0; r < 4; ++r) l_run[r] = 1.f / l_run[r];
#pragma unroll
  for (int t = 0; t < 8; ++t)
#pragma unroll
    for (int r = 0; r < 4; ++r) {
      const int row = t0 + w * 16 + q * 4 + r;
      const int col = h * HD + t * 16 + ln15;
      O[(long)row * D + col] = f2bf(o[t][r] * l_run[r]);
    }
}

extern "C" void kernel_launch(void* const* d_in, const int* in_sizes, int n_in,
                              void* d_out, int out_size, void* d_ws, size_t ws_size,
                              hipStream_t stream) {
  (void)in_sizes; (void)n_in; (void)out_size;
  const float* x      = (const float*)d_in[0];
  const float* lat    = (const float*)d_in[2];
  const float* ln_q_w = (const float*)d_in[3];
  const float* ln_q_b = (const float*)d_in[4];
  const float* ln_c_w = (const float*)d_in[5];
  const float* ln_c_b = (const float*)d_in[6];
  const float* Wq     = (const float*)d_in[7];
  const float* Wk     = (const float*)d_in[8];
  const float* Wv     = (const float*)d_in[9];
  const float* Wo     = (const float*)d_in[10];
  const float* ln_m_w = (const float*)d_in[11];
  const float* ln_m_b = (const float*)d_in[12];
  const float* W1     = (const float*)d_in[13];
  const float* W2     = (const float*)d_in[14];
  float* out = (float*)d_out;

  const long DD = (long)D * D, TD = (long)T * D, RD = (long)R * D;
  u16* p = (u16*)d_ws;
  u16* Wt   = p; p += 2 * DD;   // transposed bf16 weights (reused slot)
  u16* a_bf = p; p += TD;       // LN output / y
  u16* q_bf = p; p += TD;       // q -> o (in-place) -> g
  u16* xc   = p; p += RD;
  u16* k_bf = p; p += RD;
  u16* v_t  = p; p += RD;       // V^T (D x R)
  if (ws_size < (size_t)(p - (u16*)d_ws) * sizeof(u16)) return;

  const dim3 B(256);
  const dim3 B5(512);
  const dim3 Gw(128, 128);      // wconv grid for 4096x4096
  const dim3 Gg(16, 32);        // 256^2 GEMM: N=4096 -> 16, M=8192 -> 32

  ln_bf16<<<T, B, 0, stream>>>(x, ln_q_w, ln_q_b, a_bf);
  ln_bf16<<<R, B, 0, stream>>>(lat, ln_c_w, ln_c_b, xc);

  wconv<<<Gw, B, 0, stream>>>(Wq, Wt);
  gemm256<0><<<Gg, B5, 0, stream>>>(a_bf, Wt, q_bf, nullptr, nullptr, nullptr,
                                    0.08838834764831845f);

  wconv<<<Gw, B, 0, stream>>>(Wk, Wt);
  wconv<<<Gw, B, 0, stream>>>(Wv, Wt + DD);
  gemm_bt<1><<<dim3(64, 4), B, 0, stream>>>(xc, Wt, k_bf, v_t, nullptr, nullptr,
                                            nullptr, 1.f);

  attn_fused<<<dim3(128, 32), B, 0, stream>>>(q_bf, k_bf, v_t, q_bf);

  wconv<<<Gw, B, 0, stream>>>(Wo, Wt);
  gemm256<2><<<Gg, B5, 0, stream>>>(q_bf, Wt, nullptr, out, x, nullptr, 1.f);

  ln_bf16<<<T, B, 0, stream>>>(out, ln_m_w, ln_m_b, a_bf);

  wconv<<<Gw, B, 0, stream>>>(W1, Wt);
  gemm256<3><<<Gg, B5, 0, stream>>>(a_bf, Wt, q_bf, nullptr, nullptr, nullptr, 1.f);

  wconv<<<Gw, B, 0, stream>>>(W2, Wt);
  gemm256<4><<<Gg, B5, 0, stream>>>(q_bf, Wt, nullptr, out, nullptr, a_bf, 1.f);
}

// Round 2
// 1977.481 us; speedup vs baseline: 1.1458x; 1.0043x over previous
//
#include <hip/hip_runtime.h>
#include <hip/hip_bf16.h>
#include <math.h>

#define D 4096
#define T 8192
#define R 512
#define HD 128
#define NH 32

typedef unsigned short u16;
typedef u16 u16x8 __attribute__((ext_vector_type(8)));
typedef __bf16 bf16x8 __attribute__((ext_vector_type(8)));
typedef float f32x4 __attribute__((ext_vector_type(4)));

__device__ __forceinline__ u16 f2bf(float f) {
  unsigned u = __builtin_bit_cast(unsigned, f);
  u += 0x7FFFu + ((u >> 16) & 1u);   // RNE
  return (u16)(u >> 16);
}
__device__ __forceinline__ float bf2f(u16 b) {
  return __builtin_bit_cast(float, ((unsigned)b) << 16);
}
__device__ __forceinline__ bf16x8 ldb8(const u16* p) {
  return __builtin_bit_cast(bf16x8, *(const u16x8*)p);
}
// async global->LDS, 16B per lane; LDS dest = wave-uniform base + lane*16
__device__ __forceinline__ void async_cp16(void* gsrc, void* ldst) {
  typedef __attribute__((address_space(1))) void gvoid;
  typedef __attribute__((address_space(3))) void lvoid;
  __builtin_amdgcn_global_load_lds((gvoid*)gsrc, (lvoid*)ldst, 16, 0, 0);
}
#define MFMA(a, b, c) __builtin_amdgcn_mfma_f32_16x16x32_bf16(a, b, c, 0, 0, 0)

// raw barrier (no vmcnt drain) with compiler memory fence
__device__ __forceinline__ void wg_barrier() {
  asm volatile("" ::: "memory");
  __builtin_amdgcn_s_barrier();
  asm volatile("" ::: "memory");
}

// ---------------- LayerNorm (fp32 in -> bf16 out), one block per row ----------------
__global__ __launch_bounds__(256) void ln_bf16(
    const float* __restrict__ X, const float* __restrict__ w,
    const float* __restrict__ b, u16* __restrict__ out) {
  const int row = blockIdx.x, tid = threadIdx.x;
  const int lane = tid & 63, wv = tid >> 6;
  const float* xr = X + (long)row * D;
  float4 v[4];
  float s = 0.f, ss = 0.f;
#pragma unroll
  for (int i = 0; i < 4; ++i) {
    v[i] = *(const float4*)(xr + tid * 4 + i * 1024);
    s += v[i].x + v[i].y + v[i].z + v[i].w;
    ss += v[i].x * v[i].x + v[i].y * v[i].y + v[i].z * v[i].z + v[i].w * v[i].w;
  }
#pragma unroll
  for (int off = 32; off >= 1; off >>= 1) {
    s += __shfl_xor(s, off);
    ss += __shfl_xor(ss, off);
  }
  __shared__ float sw[4], ssw[4];
  if (lane == 0) { sw[wv] = s; ssw[wv] = ss; }
  __syncthreads();
  s = sw[0] + sw[1] + sw[2] + sw[3];
  ss = ssw[0] + ssw[1] + ssw[2] + ssw[3];
  const float mu = s * (1.f / D);
  const float var = ss * (1.f / D) - mu * mu;
  const float rstd = rsqrtf(var + 1e-5f);
#pragma unroll
  for (int i = 0; i < 4; ++i) {
    const int base = tid * 4 + i * 1024;
    const float4 wv4 = *(const float4*)(w + base);
    const float4 bv4 = *(const float4*)(b + base);
    ushort4 ov;
    ov.x = f2bf((v[i].x - mu) * rstd * wv4.x + bv4.x);
    ov.y = f2bf((v[i].y - mu) * rstd * wv4.y + bv4.y);
    ov.z = f2bf((v[i].z - mu) * rstd * wv4.z + bv4.z);
    ov.w = f2bf((v[i].w - mu) * rstd * wv4.w + bv4.w);
    *(ushort4*)(out + (long)row * D + base) = ov;
  }
}

// ------------- weight transpose + fp32->bf16 convert: W (K x N) -> Wt (N x K) -------------
__global__ __launch_bounds__(256) void wconv(const float* __restrict__ W,
                                             u16* __restrict__ Wt) {
  __shared__ float t[32][33];
  const int tx = threadIdx.x & 31, ty = threadIdx.x >> 5;
  const int n0 = blockIdx.x * 32, k0 = blockIdx.y * 32;
#pragma unroll
  for (int i = 0; i < 4; ++i)
    t[ty + i * 8][tx] = W[(long)(k0 + ty + i * 8) * D + n0 + tx];
  __syncthreads();
#pragma unroll
  for (int i = 0; i < 4; ++i)
    Wt[(long)(n0 + ty + i * 8) * D + k0 + tx] = f2bf(t[tx][ty + i * 8]);
}

// ---------------- legacy 128x128 GEMM (kept for the small KV GEMM, M=512) ----------------
// EPI: 1 = k/v split (v stored transposed)
template <int EPI>
__global__ __launch_bounds__(256) void gemm_bt(
    const u16* __restrict__ A, const u16* __restrict__ Bt, u16* __restrict__ ob,
    u16* __restrict__ ob2, float* __restrict__ of, const float* __restrict__ af,
    const u16* __restrict__ ab, float scale) {
  __shared__ u16 As[128 * 32];
  __shared__ u16 Bs[128 * 32];
  const int tid = threadIdx.x;
  const int bx = blockIdx.x, by = blockIdx.y;  // bx: n-block, by: m-block
  const int lane = tid & 63, w = tid >> 6;
  const int ln15 = lane & 15, q = lane >> 4;
  const int wm = (w >> 1) * 64, wn = (w & 1) * 64;

  const int c0 = tid, c1 = tid + 256;
  const u16* ag0 = A + (long)(by * 128 + (c0 >> 2)) * D + (c0 & 3) * 8;
  const u16* ag1 = A + (long)(by * 128 + (c1 >> 2)) * D + (c1 & 3) * 8;
  const u16* bg0 = Bt + (long)(bx * 128 + (c0 >> 2)) * D + (c0 & 3) * 8;
  const u16* bg1 = Bt + (long)(bx * 128 + (c1 >> 2)) * D + (c1 & 3) * 8;
  u16* al0 = As + (tid & ~63) * 8;
  u16* al1 = As + ((tid & ~63) + 256) * 8;
  u16* bl0 = Bs + (tid & ~63) * 8;
  u16* bl1 = Bs + ((tid & ~63) + 256) * 8;

  f32x4 acc[4][4];
#pragma unroll
  for (int i = 0; i < 4; ++i)
#pragma unroll
    for (int j = 0; j < 4; ++j) {
      f32x4 z = {0.f, 0.f, 0.f, 0.f};
      acc[i][j] = z;
    }

  for (int k0 = 0; k0 < D; k0 += 32) {
    __syncthreads();
    async_cp16((void*)(ag0 + k0), al0);
    async_cp16((void*)(ag1 + k0), al1);
    async_cp16((void*)(bg0 + k0), bl0);
    async_cp16((void*)(bg1 + k0), bl1);
    __syncthreads();
    bf16x8 av[4], bv[4];
#pragma unroll
    for (int i = 0; i < 4; ++i) av[i] = ldb8(As + (wm + i * 16 + ln15) * 32 + q * 8);
#pragma unroll
    for (int j = 0; j < 4; ++j) bv[j] = ldb8(Bs + (wn + j * 16 + ln15) * 32 + q * 8);
#pragma unroll
    for (int i = 0; i < 4; ++i)
#pragma unroll
      for (int j = 0; j < 4; ++j) acc[i][j] = MFMA(av[i], bv[j], acc[i][j]);
  }

#pragma unroll
  for (int i = 0; i < 4; ++i) {
    const int gmb = by * 128 + wm + i * 16 + q * 4;
#pragma unroll
    for (int j = 0; j < 4; ++j) {
      const int gn = bx * 128 + wn + j * 16 + ln15;
#pragma unroll
      for (int r = 0; r < 4; ++r) {
        const int gm = gmb + r;
        const float vacc = acc[i][j][r];
        const long idx = (long)gm * D + gn;
        if constexpr (EPI == 1) {
          if (gn < D)
            ob[idx] = f2bf(vacc);                       // k: (R x D)
          else
            ob2[(long)(gn - D) * R + gm] = f2bf(vacc);  // v^T: (D x R)
        } else {
          ob[idx] = f2bf(vacc * scale);
        }
      }
    }
  }
}

// ---------------- 256x256 GEMM: T2 swizzle + 2-deep counted prefetch + 2 barriers/tile ----
// C = A(MxK) * Bt(NxK)^T, K = D. 512 threads = 8 waves (2M x 4N), per-wave C = 128x64.
// LDS: double-buffered A/B tiles of 256x64 bf16, split in 128-row halves = 128 KiB.
// Pipeline: while computing tile t, buf[cur] is re-filled with tile t+2 right after
// its reads retire (barrier #1); tile t+1 residency is enforced by vmcnt(8) (the 8
// newest outstanding loads are t+2's) + barrier #2. No vmcnt(0) drain in main loop.
// EPI: 0 = bf16 store *scale; 2 = fp32 store acc + af; 3 = bf16 store gelu(acc);
//      4 = of += acc + bf2f(ab)
template <int EPI>
__global__ __launch_bounds__(512, 2) void gemm256(
    const u16* __restrict__ A, const u16* __restrict__ Bt, u16* __restrict__ ob,
    float* __restrict__ of, const float* __restrict__ af,
    const u16* __restrict__ ab, float scale) {
  __shared__ u16 As[2][2][8192];  // [buf][half(128 rows)][row*64 + swizzled col]
  __shared__ u16 Bs[2][2][8192];
  const int tid = threadIdx.x;
  const int bx = blockIdx.x, by = blockIdx.y;  // bx: n-block(256), by: m-block(256)
  const int lane = tid & 63, w = tid >> 6;
  const int ln15 = lane & 15, q = lane >> 4;
  const int wm = w >> 2, wn = w & 3;

  // ---- staging geometry: linear LDS dest, inverse-swizzled global source ----
  // physical 16B unit p = l*512 + tid -> row p>>3, physical slot p&7,
  // logical slot = (p&7) ^ (row&7)  (involution; read side applies same XOR)
  const int r0 = tid >> 3, s0 = (tid & 7) ^ (r0 & 7);
  const int r1 = 64 + r0, s1 = (tid & 7) ^ (r1 & 7);
  const long oA00 = (long)(by * 256 + r0) * D + s0 * 8;
  const long oA01 = (long)(by * 256 + r1) * D + s1 * 8;
  const long oA10 = (long)(by * 256 + 128 + r0) * D + s0 * 8;
  const long oA11 = (long)(by * 256 + 128 + r1) * D + s1 * 8;
  const long oB00 = (long)(bx * 256 + r0) * D + s0 * 8;
  const long oB01 = (long)(bx * 256 + r1) * D + s1 * 8;
  const long oB10 = (long)(bx * 256 + 128 + r0) * D + s0 * 8;
  const long oB11 = (long)(bx * 256 + 128 + r1) * D + s1 * 8;
  const int d0 = w * 512, d1 = 4096 + w * 512;  // wave-uniform LDS dest (u16 units)

  // ---- read-side swizzled offsets ----
  const int sw = ln15 & 7;
  const int cc0 = (q ^ sw) * 8;        // kk = 0: logical slot q
  const int cc1 = ((4 + q) ^ sw) * 8;  // kk = 1: logical slot 4+q
  const int baseA = ln15 * 64;
  const int baseB = (wn & 1) * 4096 + ln15 * 64;

  f32x4 acc[8][4];
#pragma unroll
  for (int i = 0; i < 8; ++i)
#pragma unroll
    for (int j = 0; j < 4; ++j) {
      f32x4 z = {0.f, 0.f, 0.f, 0.f};
      acc[i][j] = z;
    }

  auto stageA = [&](int buf, int kt) {
    async_cp16((void*)(A + oA00 + kt * 64), &As[buf][0][d0]);
    async_cp16((void*)(A + oA01 + kt * 64), &As[buf][0][d1]);
    async_cp16((void*)(A + oA10 + kt * 64), &As[buf][1][d0]);
    async_cp16((void*)(A + oA11 + kt * 64), &As[buf][1][d1]);
  };
  auto stageB = [&](int buf, int kt) {
    async_cp16((void*)(Bt + oB00 + kt * 64), &Bs[buf][0][d0]);
    async_cp16((void*)(Bt + oB01 + kt * 64), &Bs[buf][0][d1]);
    async_cp16((void*)(Bt + oB10 + kt * 64), &Bs[buf][1][d0]);
    async_cp16((void*)(Bt + oB11 + kt * 64), &Bs[buf][1][d1]);
  };

  const int NT = D / 64;  // 64 K-tiles
  // prologue: stage tiles 0 and 1 (16 loads); wait for tile 0 only (counted)
  stageA(0, 0);
  stageB(0, 0);
  stageA(1, 1);
  stageB(1, 1);
  asm volatile("s_waitcnt vmcnt(8)" ::: "memory");
  wg_barrier();

  int cur = 0;
  for (int t = 0; t < NT; ++t) {
    const bool pf = (t + 2 < NT);
    const u16* aB = &As[cur][wm][0];
    const u16* bP = &Bs[cur][wn >> 1][0];

    // ---- cluster 0: kk=0 frags (12 x ds_read_b128), 32 MFMA ----
    bf16x8 a0[8], b0[4];
#pragma unroll
    for (int im = 0; im < 8; ++im) a0[im] = ldb8(aB + im * 1024 + baseA + cc0);
#pragma unroll
    for (int nj = 0; nj < 4; ++nj) b0[nj] = ldb8(bP + nj * 1024 + baseB + cc0);
    __builtin_amdgcn_s_setprio(1);
#pragma unroll
    for (int im = 0; im < 8; ++im)
#pragma unroll
      for (int nj = 0; nj < 4; ++nj) acc[im][nj] = MFMA(a0[im], b0[nj], acc[im][nj]);
    __builtin_amdgcn_s_setprio(0);

    // ---- cluster 1 reads: kk=1 frags; then buf[cur] is fully read ----
    bf16x8 a1[8], b1[4];
#pragma unroll
    for (int im = 0; im < 8; ++im) a1[im] = ldb8(aB + im * 1024 + baseA + cc1);
#pragma unroll
    for (int nj = 0; nj < 4; ++nj) b1[nj] = ldb8(bP + nj * 1024 + baseB + cc1);
    asm volatile("s_waitcnt lgkmcnt(0)" ::: "memory");
    wg_barrier();  // barrier #1: all waves done reading buf[cur] -> it is free

    // refill buf[cur] with tile t+2 (8 loads); overlaps the kk=1 MFMA cluster
    if (pf) {
      stageA(cur, t + 2);
      stageB(cur, t + 2);
    }
    __builtin_amdgcn_s_setprio(1);
#pragma unroll
    for (int im = 0; im < 8; ++im)
#pragma unroll
      for (int nj = 0; nj < 4; ++nj) acc[im][nj] = MFMA(a1[im], b1[nj], acc[im][nj]);
    __builtin_amdgcn_s_setprio(0);

    // tile t+1 residency: its 8 loads are the oldest outstanding (issued a full
    // tile ago); the newest 8 are t+2's -> counted wait, no drain.
    if (pf)
      asm volatile("s_waitcnt vmcnt(8)" ::: "memory");
    else
      asm volatile("s_waitcnt vmcnt(0)" ::: "memory");
    wg_barrier();  // barrier #2: tile t+1 visible to all waves
    cur ^= 1;
  }

  // epilogue; C-layout: col = lane&15, row = quad*4 + reg
#pragma unroll
  for (int mi = 0; mi < 8; ++mi) {
    const int gmb = by * 256 + wm * 128 + mi * 16 + q * 4;
#pragma unroll
    for (int nj = 0; nj < 4; ++nj) {
      const int gn = bx * 256 + wn * 64 + nj * 16 + ln15;
#pragma unroll
      for (int r = 0; r < 4; ++r) {
        const int gm = gmb + r;
        const float vacc = acc[mi][nj][r];
        const long idx = (long)gm * D + gn;
        if constexpr (EPI == 0) {
          ob[idx] = f2bf(vacc * scale);
        } else if constexpr (EPI == 2) {
          of[idx] = vacc + af[idx];
        } else if constexpr (EPI == 3) {
          ob[idx] = f2bf(0.5f * vacc * (1.f + erff(vacc * 0.7071067811865475f)));
        } else {
          of[idx] = of[idx] + vacc + bf2f(ab[idx]);
        }
      }
    }
  }
}

// ---------------- fused cross-attention, online softmax ----------------
// block = (64 tokens, 1 head); Q pre-scaled by 1/sqrt(HD); O written in-place over Q.
__global__ __launch_bounds__(256) void attn_fused(const u16* Q,
                                                  const u16* __restrict__ Kb,
                                                  const u16* __restrict__ Vt,
                                                  u16* O) {
  __shared__ u16 Qs[64 * 136];   // pad 128->136 (16B mult, 2-way banks)
  __shared__ u16 Ks[64 * 136];
  __shared__ u16 Vs[128 * 72];   // V^T chunk: 128 hd x 64 latents, pad 64->72
  __shared__ u16 Ps[4][16 * 72]; // per-wave P round-trip
  const int tid = threadIdx.x;
  const int lane = tid & 63, w = tid >> 6;
  const int ln15 = lane & 15, q = lane >> 4;
  const int t0 = blockIdx.x * 64, h = blockIdx.y;

#pragma unroll
  for (int it = 0; it < 4; ++it) {
    const int c = tid + it * 256;
    const int row = c >> 4, cj = c & 15;
    *(u16x8*)(Qs + row * 136 + cj * 8) =
        *(const u16x8*)(Q + (long)(t0 + row) * D + h * HD + cj * 8);
  }

  f32x4 o[8];
  float m_run[4], l_run[4];
#pragma unroll
  for (int t = 0; t < 8; ++t) {
    f32x4 z = {0.f, 0.f, 0.f, 0.f};
    o[t] = z;
  }
#pragma unroll
  for (int r = 0; r < 4; ++r) {
    m_run[r] = -1e30f;
    l_run[r] = 0.f;
  }

  for (int ch = 0; ch < 8; ++ch) {
    const int r0 = ch * 64;
    __syncthreads();
#pragma unroll
    for (int it = 0; it < 4; ++it) {
      const int c = tid + it * 256;
      const int row = c >> 4, cj = c & 15;
      *(u16x8*)(Ks + row * 136 + cj * 8) =
          *(const u16x8*)(Kb + (long)(r0 + row) * D + h * HD + cj * 8);
    }
#pragma unroll
    for (int it = 0; it < 4; ++it) {
      const int c = tid + it * 256;
      const int hd = c >> 3, rj = c & 7;
      *(u16x8*)(Vs + hd * 72 + rj * 8) =
          *(const u16x8*)(Vt + (long)(h * HD + hd) * R + r0 + rj * 8);
    }
    __syncthreads();

    // S chunk: wave w owns tokens w*16..+15; N = 64 latents, K = 128
    f32x4 s[4];
#pragma unroll
    for (int j = 0; j < 4; ++j) {
      f32x4 z = {0.f, 0.f, 0.f, 0.f};
      s[j] = z;
    }
#pragma unroll
    for (int kk = 0; kk < 4; ++kk) {
      const bf16x8 a = ldb8(Qs + (w * 16 + ln15) * 136 + kk * 32 + q * 8);
#pragma unroll
      for (int j = 0; j < 4; ++j) {
        const bf16x8 b = ldb8(Ks + (j * 16 + ln15) * 136 + kk * 32 + q * 8);
        s[j] = MFMA(a, b, s[j]);
      }
    }
    // online softmax (rows q*4+r live in this quad's 16 lanes)
    float mx[4], rs[4];
#pragma unroll
    for (int r = 0; r < 4; ++r)
      mx[r] = fmaxf(fmaxf(s[0][r], s[1][r]), fmaxf(s[2][r], s[3][r]));
#pragma unroll
    for (int off = 8; off >= 1; off >>= 1)
#pragma unroll
      for (int r = 0; r < 4; ++r) mx[r] = fmaxf(mx[r], __shfl_xor(mx[r], off));
#pragma unroll
    for (int r = 0; r < 4; ++r) {
      const float mn = fmaxf(m_run[r], mx[r]);
      const float al = __expf(m_run[r] - mn);
      m_run[r] = mn;
      float a2 = 0.f;
#pragma unroll
      for (int j = 0; j < 4; ++j) {
        const float p = __expf(s[j][r] - mn);
        s[j][r] = p;
        a2 += p;
      }
      rs[r] = a2;
      l_run[r] *= al;
#pragma unroll
      for (int t = 0; t < 8; ++t) o[t][r] *= al;
    }
#pragma unroll
    for (int off = 8; off >= 1; off >>= 1)
#pragma unroll
      for (int r = 0; r < 4; ++r) rs[r] += __shfl_xor(rs[r], off);
#pragma unroll
    for (int r = 0; r < 4; ++r) l_run[r] += rs[r];
    // P -> LDS (C-layout regs -> row-major), then PV with A-layout reads
#pragma unroll
    for (int j = 0; j < 4; ++j)
#pragma unroll
      for (int r = 0; r < 4; ++r)
        Ps[w][(q * 4 + r) * 72 + j * 16 + ln15] = f2bf(s[j][r]);
    __syncthreads();
#pragma unroll
    for (int kk = 0; kk < 2; ++kk) {
      const bf16x8 a = ldb8(Ps[w] + ln15 * 72 + kk * 32 + q * 8);
#pragma unroll
      for (int t = 0; t < 8; ++t) {
        const bf16x8 b = ldb8(Vs + (t * 16 + ln15) * 72 + kk * 32 + q * 8);
        o[t] = MFMA(a, b, o[t]);
      }
    }
  }
#pragma unroll
  for (int r = 0; r < 4; ++r) l_run[r] = 1.f / l_run[r];
#pragma unroll
  for (int t = 0; t < 8; ++t)
#pragma unroll
    for (int r = 0; r < 4; ++r) {
      const int row = t0 + w * 16 + q * 4 + r;
      const int col = h * HD + t * 16 + ln15;
      O[(long)row * D + col] = f2bf(o[t][r] * l_run[r]);
    }
}

extern "C" void kernel_launch(void* const* d_in, const int* in_sizes, int n_in,
                              void* d_out, int out_size, void* d_ws, size_t ws_size,
                              hipStream_t stream) {
  (void)in_sizes; (void)n_in; (void)out_size;
  const float* x      = (const float*)d_in[0];
  const float* lat    = (const float*)d_in[2];
  const float* ln_q_w = (const float*)d_in[3];
  const float* ln_q_b = (const float*)d_in[4];
  const float* ln_c_w = (const float*)d_in[5];
  const float* ln_c_b = (const float*)d_in[6];
  const float* Wq     = (const float*)d_in[7];
  const float* Wk     = (const float*)d_in[8];
  const float* Wv     = (const float*)d_in[9];
  const float* Wo     = (const float*)d_in[10];
  const float* ln_m_w = (const float*)d_in[11];
  const float* ln_m_b = (const float*)d_in[12];
  const float* W1     = (const float*)d_in[13];
  const float* W2     = (const float*)d_in[14];
  float* out = (float*)d_out;

  const long DD = (long)D * D, TD = (long)T * D, RD = (long)R * D;
  u16* p = (u16*)d_ws;
  u16* Wt   = p; p += 2 * DD;   // transposed bf16 weights (reused slot)
  u16* a_bf = p; p += TD;       // LN output / y
  u16* q_bf = p; p += TD;       // q -> o (in-place) -> g
  u16* xc   = p; p += RD;
  u16* k_bf = p; p += RD;
  u16* v_t  = p; p += RD;       // V^T (D x R)
  if (ws_size < (size_t)(p - (u16*)d_ws) * sizeof(u16)) return;

  const dim3 B(256);
  const dim3 B5(512);
  const dim3 Gw(128, 128);      // wconv grid for 4096x4096
  const dim3 Gg(16, 32);        // 256^2 GEMM: N=4096 -> 16, M=8192 -> 32

  ln_bf16<<<T, B, 0, stream>>>(x, ln_q_w, ln_q_b, a_bf);
  ln_bf16<<<R, B, 0, stream>>>(lat, ln_c_w, ln_c_b, xc);

  wconv<<<Gw, B, 0, stream>>>(Wq, Wt);
  gemm256<0><<<Gg, B5, 0, stream>>>(a_bf, Wt, q_bf, nullptr, nullptr, nullptr,
                                    0.08838834764831845f);

  wconv<<<Gw, B, 0, stream>>>(Wk, Wt);
  wconv<<<Gw, B, 0, stream>>>(Wv, Wt + DD);
  gemm_bt<1><<<dim3(64, 4), B, 0, stream>>>(xc, Wt, k_bf, v_t, nullptr, nullptr,
                                            nullptr, 1.f);

  attn_fused<<<dim3(128, 32), B, 0, stream>>>(q_bf, k_bf, v_t, q_bf);

  wconv<<<Gw, B, 0, stream>>>(Wo, Wt);
  gemm256<2><<<Gg, B5, 0, stream>>>(q_bf, Wt, nullptr, out, x, nullptr, 1.f);

  ln_bf16<<<T, B, 0, stream>>>(out, ln_m_w, ln_m_b, a_bf);

  wconv<<<Gw, B, 0, stream>>>(W1, Wt);
  gemm256<3><<<Gg, B5, 0, stream>>>(a_bf, Wt, q_bf, nullptr, nullptr, nullptr, 1.f);

  wconv<<<Gw, B, 0, stream>>>(W2, Wt);
  gemm256<4><<<Gg, B5, 0, stream>>>(q_bf, Wt, nullptr, out, nullptr, a_bf, 1.f);
}